// Round 5
// baseline (216.798 us; speedup 1.0000x reference)
//
#include <hip/hip_runtime.h>
#include <hip/hip_cooperative_groups.h>

namespace cg = cooperative_groups;

#define BB 16384
#define LL 200
#define DD 100
#define VV 100000
#define NPAIR (VV / 2)          // 50000 row-pairs in phase 1
#define GRID_BLOCKS 2048        // 8 blocks/CU on 256 CUs
#define NWAVES (GRID_BLOCKS * 4)  // 8192 waves
#define ROWS_PER_WAVE (BB / NWAVES)  // 2 batch rows per wave in phase 2

// ---------------- fused cooperative kernel ----------------
// Phase 1: rowdot[v] = sum_d E[v,d]*w[d]  (half-wave per row, float4 loads)
// Phase 2: out[b] = mean_l rowdot[idx[b,l]] (wave per row, int4 idx prefetched
//          BEFORE phase 1 so idx HBM traffic overlaps the embed read)
__global__ __launch_bounds__(256, 8) void fused_kernel(
    const int4*   __restrict__ idx4,
    const float4* __restrict__ E4,
    const float4* __restrict__ w4,
    float*        __restrict__ rowdot,
    float*        __restrict__ out) {
    const int tid  = blockIdx.x * blockDim.x + threadIdx.x;
    const int wave = tid >> 6;
    const int lane = threadIdx.x & 63;
    const int half = lane >> 5;       // 0 or 1
    const int sub  = lane & 31;

    // ---- prefetch phase-2 indices (2 rows/wave, lanes 0..49, 1 int4 each)
    const bool act = lane < 50;
    int4 pf[ROWS_PER_WAVE];
    #pragma unroll
    for (int k = 0; k < ROWS_PER_WAVE; ++k) {
        int b = wave + k * NWAVES;
        pf[k] = act ? idx4[(size_t)b * 50 + lane] : make_int4(0, 0, 0, 0);
    }

    // ---- phase 1: rowdot over grid-stride row-pairs
    float4 wv = make_float4(0.f, 0.f, 0.f, 0.f);
    if (sub < 25) wv = w4[sub];
    for (int p = wave; p < NPAIR; p += NWAVES) {
        const int r = p * 2 + half;
        float s = 0.0f;
        if (sub < 25) {
            float4 v = E4[(size_t)r * 25 + sub];
            s = v.x * wv.x + v.y * wv.y + v.z * wv.z + v.w * wv.w;
        }
        #pragma unroll
        for (int off = 16; off > 0; off >>= 1)
            s += __shfl_xor(s, off, 64);
        if (sub == 0) rowdot[r] = s;
    }

    // device-scope visibility of rowdot across XCDs, then grid barrier
    __threadfence();
    cg::this_grid().sync();

    // ---- phase 2: pool (gathers hit L2-resident 400 KB rowdot table)
    #pragma unroll
    for (int k = 0; k < ROWS_PER_WAVE; ++k) {
        const int b = wave + k * NWAVES;
        float s = 0.0f;
        if (act) {
            float a = rowdot[pf[k].x];
            float c = rowdot[pf[k].y];
            float d = rowdot[pf[k].z];
            float e = rowdot[pf[k].w];
            s = (a + c) + (d + e);
        }
        #pragma unroll
        for (int off = 32; off > 0; off >>= 1)
            s += __shfl_xor(s, off, 64);
        if (lane == 0) out[b] = s * (1.0f / LL);
    }
}

// ---------------- fallback two-kernel path (proven, R3 = 28.6 us) ----------
__global__ __launch_bounds__(256) void rowdot_kernel(const float4* __restrict__ E4,
                                                     const float4* __restrict__ w4,
                                                     float* __restrict__ rowdot) {
    const int tid  = blockIdx.x * blockDim.x + threadIdx.x;
    const int wave = tid >> 6;
    const int lane = threadIdx.x & 63;
    const int half = lane >> 5;
    const int sub  = lane & 31;
    float4 wv = make_float4(0.f, 0.f, 0.f, 0.f);
    if (sub < 25) wv = w4[sub];
    const int r = wave * 2 + half;
    float s = 0.0f;
    if (sub < 25) {
        float4 v = E4[(size_t)r * 25 + sub];
        s = v.x * wv.x + v.y * wv.y + v.z * wv.z + v.w * wv.w;
    }
    #pragma unroll
    for (int off = 16; off > 0; off >>= 1)
        s += __shfl_xor(s, off, 64);
    if (sub == 0) rowdot[r] = s;
}

__global__ __launch_bounds__(256) void pool_kernel(const int4* __restrict__ idx4,
                                                   const float* __restrict__ rowdot,
                                                   float* __restrict__ out) {
    const int tid  = blockIdx.x * blockDim.x + threadIdx.x;
    const int wave = tid >> 6;
    const int lane = threadIdx.x & 63;
    float s = 0.0f;
    if (lane < 50) {
        int4 i4 = idx4[(size_t)wave * 50 + lane];
        float a = rowdot[i4.x];
        float b = rowdot[i4.y];
        float c = rowdot[i4.z];
        float d = rowdot[i4.w];
        s = (a + b) + (c + d);
    }
    #pragma unroll
    for (int off = 32; off > 0; off >>= 1)
        s += __shfl_xor(s, off, 64);
    if (lane == 0) out[wave] = s * (1.0f / LL);
}

extern "C" void kernel_launch(void* const* d_in, const int* in_sizes, int n_in,
                              void* d_out, int out_size, void* d_ws, size_t ws_size,
                              hipStream_t stream) {
    const int4*   idx4   = (const int4*)d_in[0];      // [B, L] int32 as int4
    const float4* E4     = (const float4*)d_in[1];    // [V, D] f32 as float4
    const float4* w4     = (const float4*)d_in[2];    // [D, 1] f32 as float4
    float*        out    = (float*)d_out;             // [B, 1] f32
    float*        rowdot = (float*)d_ws;              // 400 KB scratch

    void* args[5] = { (void*)&idx4, (void*)&E4, (void*)&w4,
                      (void*)&rowdot, (void*)&out };
    hipError_t err = hipLaunchCooperativeKernel((const void*)fused_kernel,
                                                dim3(GRID_BLOCKS), dim3(256),
                                                args, 0, stream);
    if (err != hipSuccess) {
        // fallback: proven two-kernel path
        rowdot_kernel<<<VV / 8, 256, 0, stream>>>(E4, w4, rowdot);
        pool_kernel<<<BB / 4, 256, 0, stream>>>(idx4, rowdot, out);
    }
}

// Round 6
// 30.730 us; speedup vs baseline: 7.0549x; 7.0549x over previous
//
#include <hip/hip_runtime.h>

#define BB 16384
#define LL 200
#define DD 100
#define VV 100000

__device__ __forceinline__ float dot4(float4 a, float4 b) {
    return a.x * b.x + a.y * b.y + a.z * b.z + a.w * b.w;
}

// Kernel 1: rowdot[v] = sum_d E[v,d] * w[d].  ONE THREAD PER ROW.
// 25 float4 loads/thread; consecutive lanes read rows 400 B apart, so each
// wave's 25.6 KB working set streams through L1 with full line utilization.
// Weights broadcast from LDS (uniform address -> no bank conflicts).
// No cross-lane reduction; stores fully coalesced.
__global__ __launch_bounds__(256) void rowdot_kernel(const float4* __restrict__ E4,
                                                     const float4* __restrict__ w4,
                                                     float* __restrict__ rowdot) {
    __shared__ float4 wsh[25];
    if (threadIdx.x < 25) wsh[threadIdx.x] = w4[threadIdx.x];
    __syncthreads();

    const int r = blockIdx.x * 256 + threadIdx.x;
    if (r >= VV) return;
    const float4* row = E4 + (size_t)r * 25;

    float a0 = 0.f, a1 = 0.f, a2 = 0.f, a3 = 0.f;
    #pragma unroll
    for (int q = 0; q < 24; q += 4) {
        float4 v0 = row[q + 0];
        float4 v1 = row[q + 1];
        float4 v2 = row[q + 2];
        float4 v3 = row[q + 3];
        a0 += dot4(v0, wsh[q + 0]);
        a1 += dot4(v1, wsh[q + 1]);
        a2 += dot4(v2, wsh[q + 2]);
        a3 += dot4(v3, wsh[q + 3]);
    }
    a0 += dot4(row[24], wsh[24]);
    rowdot[r] = (a0 + a1) + (a2 + a3);
}

// Kernel 2: out[b] = (1/L) * sum_l rowdot[idx[b,l]].  TWO ROWS PER WAVE.
// Lanes 0..49 load one int4 per row (50 x int4 = 200 idx), giving 8
// independent L2-resident gathers in flight per lane.
__global__ __launch_bounds__(256) void pool_kernel(const int4* __restrict__ idx4,
                                                   const float* __restrict__ rowdot,
                                                   float* __restrict__ out) {
    const int tid  = blockIdx.x * 256 + threadIdx.x;
    const int wave = tid >> 6;
    const int lane = threadIdx.x & 63;
    const int b0   = wave * 2;
    const int b1   = b0 + 1;

    float s0 = 0.f, s1 = 0.f;
    if (lane < 50) {
        int4 i0 = idx4[(size_t)b0 * 50 + lane];
        int4 i1 = idx4[(size_t)b1 * 50 + lane];
        float g0 = rowdot[i0.x], g1 = rowdot[i0.y];
        float g2 = rowdot[i0.z], g3 = rowdot[i0.w];
        float h0 = rowdot[i1.x], h1 = rowdot[i1.y];
        float h2 = rowdot[i1.z], h3 = rowdot[i1.w];
        s0 = (g0 + g1) + (g2 + g3);
        s1 = (h0 + h1) + (h2 + h3);
    }
    #pragma unroll
    for (int off = 32; off > 0; off >>= 1) {
        s0 += __shfl_xor(s0, off, 64);
        s1 += __shfl_xor(s1, off, 64);
    }
    if (lane == 0) {
        out[b0] = s0 * (1.0f / LL);
        out[b1] = s1 * (1.0f / LL);
    }
}

extern "C" void kernel_launch(void* const* d_in, const int* in_sizes, int n_in,
                              void* d_out, int out_size, void* d_ws, size_t ws_size,
                              hipStream_t stream) {
    const int4*   idx4   = (const int4*)d_in[0];      // [B, L] int32 as int4
    const float4* E4     = (const float4*)d_in[1];    // [V, D] f32 as float4
    const float4* w4     = (const float4*)d_in[2];    // [D, 1] f32 as float4
    float*        out    = (float*)d_out;             // [B, 1] f32
    float*        rowdot = (float*)d_ws;              // 400 KB scratch

    // 100000 rows, 1 row/thread -> 391 blocks
    rowdot_kernel<<<(VV + 255) / 256, 256, 0, stream>>>(E4, w4, rowdot);
    // 16384 batch rows, 2 rows/wave, 4 waves/block -> 2048 blocks
    pool_kernel<<<BB / 8, 256, 0, stream>>>(idx4, rowdot, out);
}